// Round 8
// baseline (14930.453 us; speedup 1.0000x reference)
//
#include <hip/hip_runtime.h>
#include <math.h>

// Problem constants (fixed by the reference)
constexpr int N_ = 101, H_ = 128, NH_ = 8, HD_ = 16;
constexpr int SK = 129;              // padded LDS stride for K tables
constexpr float EPS_ = 1e-5f;

// ===================== 2-batch kernel (dynamic LDS, 116.8 KB) =====================
// LDS word offsets
constexpr int OFF_KH0 = 0;                    // 13032 (101*129 padded)
constexpr int OFF_KH1 = OFF_KH0 + 13032;      // 13032
constexpr int OFF_BUF0 = OFF_KH1 + 13032;     // 816
constexpr int OFF_BUF1 = OFF_BUF0 + 816;      // 816
constexpr int OFF_RED0 = OFF_BUF1 + 816;      // 512
constexpr int OFF_RED1 = OFF_RED0 + 512;      // 512
constexpr int OFF_DV0 = OFF_RED1 + 512;       // 128
constexpr int OFF_DV1 = OFF_DV0 + 128;        // 128
constexpr int OFF_MB0 = OFF_DV1 + 128;        // 104
constexpr int OFF_MB1 = OFF_MB0 + 104;        // 104
constexpr int OFF_SC  = OFF_MB1 + 104;        // 8
constexpr int LDS_WORDS2 = OFF_SC + 8;        // 29192 words = 116,768 B
constexpr int LDS_BYTES2 = LDS_WORDS2 * 4;

__global__ __launch_bounds__(512, 2) void gat_decoder2(
    const float* __restrict__ enc, const float* __restrict__ pool,
    const float* __restrict__ capac, const float* __restrict__ dem,
    const float* __restrict__ fcw, const float* __restrict__ fc1w,
    const float* __restrict__ lng, const float* __restrict__ lnb,
    const float* __restrict__ wq, const float* __restrict__ wk,
    const float* __restrict__ wvm, const float* __restrict__ wo,
    const float* __restrict__ kpw, const float* __restrict__ plg,
    const float* __restrict__ plb, const int* __restrict__ tp,
    float* __restrict__ out, int Bv, int ns)
{
  extern __shared__ float sm[];
  const int tid  = threadIdx.x;
  const int lane = tid & 63;
  const int wvid = tid >> 6;        // wave id 0..7 (= head id in DE phase)
  const int j    = tid & 127;       // output column
  const int s    = tid >> 7;        // k-slice 0..3
  const int w1   = wvid & 1;        // j-half of this wave
  const int b0   = blockIdx.x * 2;
  const int b1   = b0 + 1;

  const float NEG_INF = -__builtin_inff();
  int ti = tp[0];
  float Tf = (ti > 1000000 || ti < -1000000) ? __int_as_float((int)ti) : (float)ti;
  const float inv_sqrt_h = 1.0f / sqrtf(128.0f);
  const float PSUM_CONST = 1.0f + (float)N_ * 1e-10f;

  const float* enc0 = enc + (size_t)b0 * (N_ * H_);
  const float* enc1 = enc + (size_t)b1 * (N_ * H_);

  float* KH0 = sm + OFF_KH0; float* KH1 = sm + OFF_KH1;
  float* BUF0 = sm + OFF_BUF0; float* BUF1 = sm + OFF_BUF1;
  float* RED0 = sm + OFF_RED0; float* RED1 = sm + OFF_RED1;
  float* DV0 = sm + OFF_DV0;  float* DV1 = sm + OFF_DV1;
  float* MB0 = sm + OFF_MB0;  float* MB1 = sm + OFF_MB1;
  int*   SCI = ((int*)sm) + OFF_SC;

  const int g  = __builtin_amdgcn_readfirstlane(s);
  const int r0 = g * 26;
  const int nr = (g == 3) ? 23 : 26;

  // ---------- precompute Kh0/Kh1 into LDS ----------
  for (int bb = 0; bb < 2; ++bb) {
    const float* eb = bb ? enc1 : enc0;
    float* KHb = bb ? KH1 : KH0;
    float acc[26];
    #pragma unroll
    for (int t = 0; t < 26; ++t) acc[t] = 0.f;
    for (int k0 = 0; k0 < H_; k0 += 8) {
      float w8[8];
      #pragma unroll
      for (int kk = 0; kk < 8; ++kk) w8[kk] = wk[(k0 + kk) * H_ + j];
      #pragma unroll
      for (int t = 0; t < 26; ++t) {
        if (t < nr) {
          const float* ep = eb + (r0 + t) * H_ + k0;   // wave-uniform address
          #pragma unroll
          for (int kk = 0; kk < 8; ++kk) acc[t] = fmaf(ep[kk], w8[kk], acc[t]);
        }
      }
    }
    #pragma unroll
    for (int t = 0; t < 26; ++t)
      if (t < nr) KHb[(r0 + t) * SK + j] = acc[t];
  }

  // ---------- Kp, V column slices in registers (per batch, sequential loops) ----------
  float kp0_r[26], vh0_r[26], kp1_r[26], vh1_r[26];
  {
    #pragma unroll
    for (int t = 0; t < 26; ++t) { kp0_r[t]=0.f; vh0_r[t]=0.f; }
    for (int k0 = 0; k0 < H_; k0 += 8) {
      float wp8[8], wv8[8];
      #pragma unroll
      for (int kk = 0; kk < 8; ++kk) { wp8[kk] = kpw[(k0+kk)*H_ + j]; wv8[kk] = wvm[(k0+kk)*H_ + j]; }
      #pragma unroll
      for (int t = 0; t < 26; ++t) if (t < nr) {
        const float* ea = enc0 + (r0 + t) * H_ + k0;
        #pragma unroll
        for (int kk = 0; kk < 8; ++kk) {
          kp0_r[t] = fmaf(ea[kk], wp8[kk], kp0_r[t]);
          vh0_r[t] = fmaf(ea[kk], wv8[kk], vh0_r[t]);
        }
      }
    }
    #pragma unroll
    for (int t = 0; t < 26; ++t) { kp1_r[t]=0.f; vh1_r[t]=0.f; }
    for (int k0 = 0; k0 < H_; k0 += 8) {
      float wp8[8], wv8[8];
      #pragma unroll
      for (int kk = 0; kk < 8; ++kk) { wp8[kk] = kpw[(k0+kk)*H_ + j]; wv8[kk] = wvm[(k0+kk)*H_ + j]; }
      #pragma unroll
      for (int t = 0; t < 26; ++t) if (t < nr) {
        const float* eb = enc1 + (r0 + t) * H_ + k0;
        #pragma unroll
        for (int kk = 0; kk < 8; ++kk) {
          kp1_r[t] = fmaf(eb[kk], wp8[kk], kp1_r[t]);
          vh1_r[t] = fmaf(eb[kk], wv8[kk], vh1_r[t]);
        }
      }
    }
  }

  // ---------- fc, wo in registers (shared weights) ----------
  float fc_r[32], wo_r[32];
  #pragma unroll
  for (int r = 0; r < 32; ++r) {
    fc_r[r] = fcw[(s * 32 + r) * H_ + j];
    wo_r[r] = wo[(s * 32 + r) * H_ + j];
  }

  // ---------- pool_proc partials for both batches ----------
  {
    const float* pb0 = pool + (size_t)b0 * H_;
    const float* pb1 = pool + (size_t)b1 * H_;
    float p0 = 0.f, p1 = 0.f;
    #pragma unroll
    for (int r = 0; r < 32; ++r) {
      const float w = fc1w[(s * 32 + r) * H_ + j];
      p0 = fmaf(pb0[s * 32 + r], w, p0);
      p1 = fmaf(pb1[s * 32 + r], w, p1);
    }
    RED0[s * H_ + j] = p0;
    RED1[s * H_ + j] = p1;
  }
  if (tid == 0) { SCI[0] = 0; SCI[1] = 0; }
  __syncthreads();

  // ---------- waves 0/1 hold per-batch decode state in registers ----------
  float capv=0.f, cap=0.f, lpsum=0.f, demA=0.f, demC=0.f, ppA=0.f, ppC=0.f;
  float lngA=0.f,lngC=0.f,lnbA=0.f,lnbC=0.f,plgA=0.f,plgC=0.f,plbA=0.f,plbC=0.f;
  float fcapA=0.f, fcapC=0.f;
  int vis = 0; bool m1a=false, m1c=false;
  if (wvid < 2) {
    const int bb = b0 + wvid;
    const float* REDb = (wvid == 0) ? RED0 : RED1;
    float* MBb = (wvid == 0) ? MB0 : MB1;
    capv = capac[bb]; cap = capv;
    demA = dem[(size_t)bb * N_ + lane];
    demC = (lane + 64 < N_) ? dem[(size_t)bb * N_ + lane + 64] : 0.f;
    ppA = REDb[lane] + REDb[128+lane] + REDb[256+lane] + REDb[384+lane];
    ppC = REDb[64+lane] + REDb[192+lane] + REDb[320+lane] + REDb[448+lane];
    lngA = lng[lane]; lngC = lng[lane+64];
    lnbA = lnb[lane]; lnbC = lnb[lane+64];
    plgA = plg[lane]; plgC = plg[lane+64];
    plbA = plb[lane]; plbC = plb[lane+64];
    fcapA = fcw[128*H_ + lane]; fcapC = fcw[128*H_ + 64 + lane];
    bool infA = (lane >= 1) && (demA > cap);
    bool infB = (lane + 64 >= N_) || (demC > cap);
    bool feasA = (lane >= 1) && !infA;
    bool feasB = (lane + 64 < N_) && !infB;
    const bool anyf = __any(feasA || feasB);
    MBb[lane] = (lane == 0) ? (anyf ? 1.f : 0.f) : (infA ? 1.f : 0.f);
    if (lane + 64 < N_) MBb[lane + 64] = infB ? 1.f : 0.f;
  }
  __syncthreads();

  // ---------- decode loop ----------
  for (int i = 0; i < ns; ++i) {
    const int pidx0 = __builtin_amdgcn_readfirstlane(SCI[0]);
    const int pidx1 = __builtin_amdgcn_readfirstlane(SCI[1]);

    // B: d-partials = inp @ fc_w (both batches, fc resident)
    {
      const float* ep0 = enc0 + (size_t)pidx0 * H_ + s * 32;
      const float* ep1 = enc1 + (size_t)pidx1 * H_ + s * 32;
      float p0 = 0.f, p1 = 0.f;
      #pragma unroll
      for (int r = 0; r < 32; ++r) {
        p0 = fmaf(fc_r[r], ep0[r], p0);
        p1 = fmaf(fc_r[r], ep1[r], p1);
      }
      RED0[s*H_ + j] = p0; RED1[s*H_ + j] = p1;
    }
    __syncthreads();                                            // S1

    // B-LN (wave 0 -> batch0, wave 1 -> batch1)
    if (wvid < 2) {
      const float* REDb = (wvid == 0) ? RED0 : RED1;
      float* DVb = (wvid == 0) ? DV0 : DV1;
      float a = REDb[lane]+REDb[128+lane]+REDb[256+lane]+REDb[384+lane] + cap*fcapA + ppA;
      float c = REDb[64+lane]+REDb[192+lane]+REDb[320+lane]+REDb[448+lane] + cap*fcapC + ppC;
      float ssum = a + c;
      #pragma unroll
      for (int o = 32; o; o >>= 1) ssum += __shfl_xor(ssum, o, 64);
      const float mu = ssum * (1.f/128.f);
      const float da = a - mu, dc = c - mu;
      float vvv = da*da + dc*dc;
      #pragma unroll
      for (int o = 32; o; o >>= 1) vvv += __shfl_xor(vvv, o, 64);
      const float inv = 1.0f / sqrtf(vvv * (1.f/128.f) + EPS_);
      DVb[lane]    = da * inv * lngA + lnbA;
      DVb[lane+64] = dc * inv * lngC + lnbC;
    }
    __syncthreads();                                            // S2

    // C: q-partials = d @ wq (wq STREAMED from L2; DV reads are LDS broadcasts)
    {
      float q0p = 0.f, q1p = 0.f;
      #pragma unroll
      for (int r = 0; r < 32; ++r) {
        const float wqv = wq[(s * 32 + r) * H_ + j];
        q0p = fmaf(wqv, DV0[s * 32 + r], q0p);
        q1p = fmaf(wqv, DV1[s * 32 + r], q1p);
      }
      RED0[s*H_ + j] = q0p; RED1[s*H_ + j] = q1p;
    }
    __syncthreads();                                            // S3

    // DE (wave = head): q-sum + logits from LDS K + softmax, both batches
    {
      const int n1 = lane, n2 = lane + 64;
      // batch 0
      {
        float qh[16];
        #pragma unroll
        for (int d = 0; d < 16; ++d) {
          const int c0 = wvid * 16 + d;
          qh[d] = RED0[c0] + RED0[128 + c0] + RED0[256 + c0] + RED0[384 + c0];
        }
        const float* k1 = KH0 + n1 * SK + wvid * HD_;
        float a1 = 0.f;
        #pragma unroll
        for (int d = 0; d < 16; ++d) a1 = fmaf(qh[d], k1[d], a1);
        a1 = (MB0[n1] > 0.f) ? NEG_INF : a1 * 0.25f;
        float a2 = NEG_INF;
        if (n2 < N_) {
          const float* k2 = KH0 + n2 * SK + wvid * HD_;
          float t2 = 0.f;
          #pragma unroll
          for (int d = 0; d < 16; ++d) t2 = fmaf(qh[d], k2[d], t2);
          a2 = (MB0[n2] > 0.f) ? NEG_INF : t2 * 0.25f;
        }
        float mx = fmaxf(a1, a2);
        #pragma unroll
        for (int o = 32; o; o >>= 1) mx = fmaxf(mx, __shfl_xor(mx, o, 64));
        float e1 = expf(a1 - mx);
        float e2 = (n2 < N_) ? expf(a2 - mx) : 0.f;
        float ssum = e1 + e2;
        #pragma unroll
        for (int o = 32; o; o >>= 1) ssum += __shfl_xor(ssum, o, 64);
        BUF0[wvid * N_ + n1] = e1 / ssum;
        if (n2 < N_) BUF0[wvid * N_ + n2] = e2 / ssum;
      }
      // batch 1
      {
        float qh[16];
        #pragma unroll
        for (int d = 0; d < 16; ++d) {
          const int c0 = wvid * 16 + d;
          qh[d] = RED1[c0] + RED1[128 + c0] + RED1[256 + c0] + RED1[384 + c0];
        }
        const float* k1 = KH1 + n1 * SK + wvid * HD_;
        float a1 = 0.f;
        #pragma unroll
        for (int d = 0; d < 16; ++d) a1 = fmaf(qh[d], k1[d], a1);
        a1 = (MB1[n1] > 0.f) ? NEG_INF : a1 * 0.25f;
        float a2 = NEG_INF;
        if (n2 < N_) {
          const float* k2 = KH1 + n2 * SK + wvid * HD_;
          float t2 = 0.f;
          #pragma unroll
          for (int d = 0; d < 16; ++d) t2 = fmaf(qh[d], k2[d], t2);
          a2 = (MB1[n2] > 0.f) ? NEG_INF : t2 * 0.25f;
        }
        float mx = fmaxf(a1, a2);
        #pragma unroll
        for (int o = 32; o; o >>= 1) mx = fmaxf(mx, __shfl_xor(mx, o, 64));
        float e1 = expf(a1 - mx);
        float e2 = (n2 < N_) ? expf(a2 - mx) : 0.f;
        float ssum = e1 + e2;
        #pragma unroll
        for (int o = 32; o; o >>= 1) ssum += __shfl_xor(ssum, o, 64);
        BUF1[wvid * N_ + n1] = e1 / ssum;
        if (n2 < N_) BUF1[wvid * N_ + n2] = e2 / ssum;
      }
    }
    __syncthreads();                                            // S4

    // F1: x-partials = attn @ V (V in registers, both batches)
    {
      const float* aw0 = BUF0 + (j >> 4) * N_ + r0;
      const float* aw1 = BUF1 + (j >> 4) * N_ + r0;
      float x0 = 0.f, x1 = 0.f;
      #pragma unroll
      for (int t = 0; t < 26; ++t) if (t < nr) {
        x0 = fmaf(aw0[t], vh0_r[t], x0);
        x1 = fmaf(aw1[t], vh1_r[t], x1);
      }
      RED0[s*H_ + j] = x0; RED1[s*H_ + j] = x1;
    }
    __syncthreads();                                            // S5

    // F3: y-partials = x @ wo (x folded inline via float4; wo resident)
    {
      float y0 = 0.f, y1 = 0.f;
      #pragma unroll
      for (int r4 = 0; r4 < 8; ++r4) {
        const int k = s * 32 + r4 * 4;
        float4 u0 = *(const float4*)&RED0[k];
        float4 u1 = *(const float4*)&RED0[128 + k];
        float4 u2 = *(const float4*)&RED0[256 + k];
        float4 u3 = *(const float4*)&RED0[384 + k];
        y0 = fmaf(wo_r[r4*4+0], ((u0.x + u1.x) + u2.x) + u3.x, y0);
        y0 = fmaf(wo_r[r4*4+1], ((u0.y + u1.y) + u2.y) + u3.y, y0);
        y0 = fmaf(wo_r[r4*4+2], ((u0.z + u1.z) + u2.z) + u3.z, y0);
        y0 = fmaf(wo_r[r4*4+3], ((u0.w + u1.w) + u2.w) + u3.w, y0);
        float4 t0 = *(const float4*)&RED1[k];
        float4 t1 = *(const float4*)&RED1[128 + k];
        float4 t2 = *(const float4*)&RED1[256 + k];
        float4 t3 = *(const float4*)&RED1[384 + k];
        y1 = fmaf(wo_r[r4*4+0], ((t0.x + t1.x) + t2.x) + t3.x, y1);
        y1 = fmaf(wo_r[r4*4+1], ((t0.y + t1.y) + t2.y) + t3.y, y1);
        y1 = fmaf(wo_r[r4*4+2], ((t0.z + t1.z) + t2.z) + t3.z, y1);
        y1 = fmaf(wo_r[r4*4+3], ((t0.w + t1.w) + t2.w) + t3.w, y1);
      }
      BUF0[s*H_ + j] = y0; BUF1[s*H_ + j] = y1;
    }
    __syncthreads();                                            // S6

    // F4-LN (waves 0/1): sum + LayerNorm(ptr) -> DV (= xn)
    if (wvid < 2) {
      const float* BUFb = (wvid == 0) ? BUF0 : BUF1;
      float* DVb = (wvid == 0) ? DV0 : DV1;
      float a = BUFb[lane]+BUFb[128+lane]+BUFb[256+lane]+BUFb[384+lane];
      float c = BUFb[64+lane]+BUFb[192+lane]+BUFb[320+lane]+BUFb[448+lane];
      float ssum = a + c;
      #pragma unroll
      for (int o = 32; o; o >>= 1) ssum += __shfl_xor(ssum, o, 64);
      const float mu = ssum * (1.f/128.f);
      const float da = a - mu, dc = c - mu;
      float vvv = da*da + dc*dc;
      #pragma unroll
      for (int o = 32; o; o >>= 1) vvv += __shfl_xor(vvv, o, 64);
      const float inv = 1.0f / sqrtf(vvv * (1.f/128.f) + EPS_);
      DVb[lane]    = da * inv * plgA + plbA;
      DVb[lane+64] = dc * inv * plgC + plbC;
    }
    __syncthreads();                                            // S7

    // G1: comp halves via register Kp + 64-lane butterflies (both batches)
    {
      const float d0j = DV0[j], d1j = DV1[j];
      #pragma unroll
      for (int t = 0; t < 26; ++t) if (t < nr) {
        float v0 = d0j * kp0_r[t];
        float v1 = d1j * kp1_r[t];
        #pragma unroll
        for (int o = 32; o; o >>= 1) { v0 += __shfl_xor(v0, o, 64); v1 += __shfl_xor(v1, o, 64); }
        if (lane == 0) { RED0[w1*256 + r0 + t] = v0; RED1[w1*256 + r0 + t] = v1; }
      }
    }
    __syncthreads();                                            // S8

    // G2 (wave 0 -> batch0, wave 1 -> batch1): argmax, lp, state, next masks
    if (wvid < 2) {
      const float* REDb = (wvid == 0) ? RED0 : RED1;
      float* MBb = (wvid == 0) ? MB0 : MB1;
      const int bb = b0 + wvid;
      const int n1 = lane, n2 = lane + 64;
      const bool mbA = (MBb[n1] > 0.f);
      const bool mbB = (n2 >= N_) || (MBb[n2] > 0.f);
      const bool allmb = __all(mbA && mbB);
      float c1 = mbA ? NEG_INF : (REDb[n1] + REDb[256+n1]) * inv_sqrt_h / Tf;
      float c2 = (n2 < N_ && !mbB) ? (REDb[n2] + REDb[256+n2]) * inv_sqrt_h / Tf : NEG_INF;
      if (allmb) { c1 = 0.f; c2 = (n2 < N_) ? 0.f : NEG_INF; }
      float bv = c1; int bi = n1;
      if (c2 > bv) { bv = c2; bi = n2; }
      #pragma unroll
      for (int o = 32; o; o >>= 1) {
        float ov = __shfl_xor(bv, o, 64);
        int   oi = __shfl_xor(bi, o, 64);
        if (ov > bv || (ov == bv && oi < bi)) { bv = ov; bi = oi; }
      }
      float e1 = expf(c1 - bv);
      float e2 = (n2 < N_) ? expf(c2 - bv) : 0.f;
      float ssum = e1 + e2;
      #pragma unroll
      for (int o = 32; o; o >>= 1) ssum += __shfl_xor(ssum, o, 64);
      float lp = logf((1.0f / ssum + 1e-10f) / PSUM_CONST);
      if (vis >= N_ - 1) lp = 0.f;
      lpsum += lp;
      const float dsel = (bi < 64) ? __shfl(demA, bi, 64) : __shfl(demC, bi - 64, 64);
      cap = (bi == 0) ? capv : (cap - dsel);
      if (bi != 0) {
        const bool newly = ((bi == n1) && !m1a) || ((bi == n2) && !m1c);
        if (__any(newly)) vis += 1;
        m1a = m1a || (bi == n1);
        m1c = m1c || (bi == n2);
      }
      bool infA = (n1 >= 1) && (m1a || demA > cap);
      bool infB = (n2 >= N_) || m1c || (demC > cap);
      bool feasA = (n1 >= 1) && !infA;
      bool feasB = (n2 < N_) && !infB;
      const bool anyf = __any(feasA || feasB);
      const bool depot_m = anyf && (bi == 0);
      MBb[n1] = (n1 == 0) ? (depot_m ? 1.f : 0.f) : (infA ? 1.f : 0.f);
      if (n2 < N_) MBb[n2] = infB ? 1.f : 0.f;
      if (lane == 0) {
        SCI[wvid] = bi;
        out[(size_t)bb * (ns + 2) + 1 + i] = (float)bi;
      }
    }
    __syncthreads();                                            // S9
  }

  if (wvid < 2 && lane == 0) {
    const int bb = b0 + wvid;
    const int last = SCI[wvid];
    out[(size_t)bb * (ns + 2)] = 0.f;
    out[(size_t)bb * (ns + 2) + ns + 1] = (last == 0) ? -1.f : 0.f;
    out[(size_t)Bv * (ns + 2) + bb] = lpsum;   // log_p
  }
}

// ===================== fallback: round-3 kernel (static 60 KB LDS, known-pass) =====================
constexpr int FOFF_KH  = 0;
constexpr int FOFF_BUF = FOFF_KH + N_ * SK;
constexpr int FOFF_RED = FOFF_BUF + NH_ * N_;
constexpr int FOFF_MB  = FOFF_RED + 512;
constexpr int FOFF_M1  = FOFF_MB + N_;
constexpr int FOFF_DV  = FOFF_M1 + N_;
constexpr int FOFF_QV  = FOFF_DV + H_;
constexpr int FOFF_XV  = FOFF_QV + H_;
constexpr int FOFF_PP  = FOFF_XV + H_;
constexpr int FOFF_IV  = FOFF_PP + H_;
constexpr int FOFF_SC  = FOFF_IV + H_;
constexpr int FLDS_WORDS = FOFF_SC + 8;

__global__ __launch_bounds__(512, 2) void gat_decoder_fb(
    const float* __restrict__ enc, const float* __restrict__ pool,
    const float* __restrict__ capac, const float* __restrict__ dem,
    const float* __restrict__ fcw, const float* __restrict__ fc1w,
    const float* __restrict__ lng, const float* __restrict__ lnb,
    const float* __restrict__ wq, const float* __restrict__ wk,
    const float* __restrict__ wvm, const float* __restrict__ wo,
    const float* __restrict__ kpw, const float* __restrict__ plg,
    const float* __restrict__ plb, const int* __restrict__ tp,
    float* __restrict__ out, int Bv, int ns)
{
  __shared__ float sm[FLDS_WORDS];
  const int tid  = threadIdx.x;
  const int b    = blockIdx.x;
  const int lane = tid & 63;
  const int j    = tid & 127;
  const int s    = tid >> 7;
  const int w1   = (tid >> 6) & 1;

  const float NEG_INF = -__builtin_inff();
  int ti = tp[0];
  float Tf = (ti > 1000000 || ti < -1000000) ? __int_as_float((int)ti) : (float)ti;
  const float inv_sqrt_hd = 0.25f;
  const float inv_sqrt_h  = 1.0f / sqrtf(128.0f);
  const float* encb = enc + (size_t)b * (N_ * H_);

  float* KH = sm + FOFF_KH;
  float* BUF = sm + FOFF_BUF; float* RED = sm + FOFF_RED;
  float* MB = sm + FOFF_MB; float* M1 = sm + FOFF_M1;
  float* DV = sm + FOFF_DV; float* QV = sm + FOFF_QV; float* XV = sm + FOFF_XV;
  float* PP = sm + FOFF_PP; float* IV = sm + FOFF_IV;
  int*   SCI = ((int*)sm) + FOFF_SC;
  float* SCF = sm + FOFF_SC;

  const int g  = __builtin_amdgcn_readfirstlane(tid >> 7);
  const int r0 = g * 26;
  const int nr = (g == 3) ? 23 : 26;

  {
    float acc[26];
    #pragma unroll
    for (int t = 0; t < 26; ++t) acc[t] = 0.f;
    for (int k0 = 0; k0 < H_; k0 += 8) {
      float w8[8];
      #pragma unroll
      for (int kk = 0; kk < 8; ++kk) w8[kk] = wk[(k0 + kk) * H_ + j];
      #pragma unroll
      for (int t = 0; t < 26; ++t) if (t < nr) {
        const float* ep = encb + (r0 + t) * H_ + k0;
        #pragma unroll
        for (int kk = 0; kk < 8; ++kk) acc[t] = fmaf(ep[kk], w8[kk], acc[t]);
      }
    }
    #pragma unroll
    for (int t = 0; t < 26; ++t) if (t < nr) KH[(r0 + t) * SK + j] = acc[t];
  }
  float kp_r[26], vh_r[26];
  {
    #pragma unroll
    for (int t = 0; t < 26; ++t) { kp_r[t] = 0.f; vh_r[t] = 0.f; }
    for (int k0 = 0; k0 < H_; k0 += 8) {
      float wp8[8], wv8[8];
      #pragma unroll
      for (int kk = 0; kk < 8; ++kk) { wp8[kk] = kpw[(k0+kk)*H_+j]; wv8[kk] = wvm[(k0+kk)*H_+j]; }
      #pragma unroll
      for (int t = 0; t < 26; ++t) if (t < nr) {
        const float* ep = encb + (r0 + t) * H_ + k0;
        #pragma unroll
        for (int kk = 0; kk < 8; ++kk) {
          kp_r[t] = fmaf(ep[kk], wp8[kk], kp_r[t]);
          vh_r[t] = fmaf(ep[kk], wv8[kk], vh_r[t]);
        }
      }
    }
  }
  {
    const float* pb = pool + (size_t)b * H_;
    float p = 0.f;
    #pragma unroll
    for (int r = 0; r < 32; ++r) p = fmaf(pb[s*32+r], fc1w[(s*32+r)*H_+j], p);
    RED[s * H_ + j] = p;
  }
  for (int n = tid; n < N_; n += 512) M1[n] = 0.f;
  if (tid == 0) { SCI[0] = 0; SCF[1] = capac[b]; SCF[2] = 0.f; SCI[3] = 0; }
  __syncthreads();
  if (tid < 128) PP[j] = RED[j] + RED[128+j] + RED[256+j] + RED[384+j];
  __syncthreads();

  float wq_r[32], wo_r[32], fc_r[32];
  #pragma unroll
  for (int r = 0; r < 32; ++r) {
    wq_r[r] = wq[(s*32+r)*H_+j];
    wo_r[r] = wo[(s*32+r)*H_+j];
    fc_r[r] = fcw[(s*32+r)*H_+j];
  }
  const float fcap = fcw[128*H_+j];

  for (int i = 0; i < ns; ++i) {
    const int pidx = SCI[0];
    if (tid < 64) {
      const float cap = SCF[1];
      const bool newly = (i > 0) && (pidx != 0);
      const int n1 = lane, n2 = lane + 64;
      bool vis1 = (M1[n1] > 0.f) || (newly && n1 == pidx);
      bool inf1 = (n1 >= 1) && (vis1 || dem[(size_t)b*N_+n1] > cap);
      bool feas1 = (n1 >= 1) && !inf1;
      bool inf2 = true, feas2 = false;
      if (n2 < N_) {
        bool vis2 = (M1[n2] > 0.f) || (newly && n2 == pidx);
        inf2 = vis2 || (dem[(size_t)b*N_+n2] > cap);
        feas2 = !inf2;
      }
      const bool anyf = __any(feas1 || feas2);
      const bool allc = !anyf;
      const bool depot_m = allc ? false : ((i == 0) ? true : ((pidx == 0) && anyf));
      MB[n1] = (n1 == 0) ? (depot_m ? 1.f : 0.f) : (inf1 ? 1.f : 0.f);
      if (n2 < N_) MB[n2] = inf2 ? 1.f : 0.f;
      if (newly && (n1 == pidx || n2 == pidx)) {
        if (M1[pidx] == 0.f) { M1[pidx] = 1.f; SCI[3] = SCI[3] + 1; }
      }
    } else if (tid >= 128 && tid < 256) {
      IV[tid-128] = encb[(size_t)pidx*H_ + (tid-128)];
    }
    __syncthreads();
    {
      float part = 0.f;
      #pragma unroll
      for (int r = 0; r < 32; ++r) part = fmaf(fc_r[r], IV[s*32+r], part);
      RED[s*H_+j] = part;
    }
    __syncthreads();
    if (tid < 128) {
      float dsum = RED[j]+RED[128+j]+RED[256+j]+RED[384+j];
      dsum += SCF[1]*fcap + PP[j];
      DV[j] = dsum;
    }
    __syncthreads();
    if (tid < 64) {
      float a = DV[lane], c = DV[lane+64];
      float ssum = a + c;
      #pragma unroll
      for (int o = 32; o; o >>= 1) ssum += __shfl_xor(ssum, o, 64);
      const float mu = ssum * (1.f/128.f);
      const float da = a-mu, dc = c-mu;
      float vv = da*da + dc*dc;
      #pragma unroll
      for (int o = 32; o; o >>= 1) vv += __shfl_xor(vv, o, 64);
      const float inv = 1.0f / sqrtf(vv*(1.f/128.f)+EPS_);
      DV[lane]    = da*inv*lng[lane] + lnb[lane];
      DV[lane+64] = dc*inv*lng[lane+64] + lnb[lane+64];
    }
    __syncthreads();
    {
      float part = 0.f;
      #pragma unroll
      for (int r = 0; r < 32; ++r) part = fmaf(wq_r[r], DV[s*32+r], part);
      RED[s*H_+j] = part;
    }
    __syncthreads();
    if (tid < 128) QV[j] = RED[j]+RED[128+j]+RED[256+j]+RED[384+j];
    __syncthreads();
    for (int t = tid; t < NH_*N_; t += 512) {
      const int h = t / N_, n = t - h*N_;
      const float* kh = KH + n*SK + h*HD_;
      const float* qh = QV + h*HD_;
      float a0 = 0.f;
      #pragma unroll
      for (int d0 = 0; d0 < HD_; ++d0) a0 = fmaf(qh[d0], kh[d0], a0);
      BUF[h*N_+n] = (MB[n] > 0.f) ? NEG_INF : a0*inv_sqrt_hd;
    }
    __syncthreads();
    {
      const int h = tid >> 6;
      float* lg = BUF + h*N_;
      float v1 = lg[lane];
      float v2 = (lane+64 < N_) ? lg[lane+64] : NEG_INF;
      float mx = fmaxf(v1, v2);
      #pragma unroll
      for (int o = 32; o; o >>= 1) mx = fmaxf(mx, __shfl_xor(mx, o, 64));
      float e1 = expf(v1-mx);
      float e2 = (lane+64 < N_) ? expf(v2-mx) : 0.f;
      float ssum = e1+e2;
      #pragma unroll
      for (int o = 32; o; o >>= 1) ssum += __shfl_xor(ssum, o, 64);
      lg[lane] = e1/ssum;
      if (lane+64 < N_) lg[lane+64] = e2/ssum;
    }
    __syncthreads();
    {
      const float* aw = BUF + (j>>4)*N_ + r0;
      float part = 0.f;
      #pragma unroll
      for (int t = 0; t < 26; ++t) if (t < nr) part = fmaf(aw[t], vh_r[t], part);
      RED[s*H_+j] = part;
    }
    __syncthreads();
    if (tid < 128) XV[j] = RED[j]+RED[128+j]+RED[256+j]+RED[384+j];
    __syncthreads();
    {
      float part = 0.f;
      #pragma unroll
      for (int r = 0; r < 32; ++r) part = fmaf(wo_r[r], XV[s*32+r], part);
      RED[s*H_+j] = part;
    }
    __syncthreads();
    if (tid < 128) DV[j] = RED[j]+RED[128+j]+RED[256+j]+RED[384+j];
    __syncthreads();
    if (tid < 64) {
      float a = DV[lane], c = DV[lane+64];
      float ssum = a + c;
      #pragma unroll
      for (int o = 32; o; o >>= 1) ssum += __shfl_xor(ssum, o, 64);
      const float mu = ssum * (1.f/128.f);
      const float da = a-mu, dc = c-mu;
      float vv = da*da + dc*dc;
      #pragma unroll
      for (int o = 32; o; o >>= 1) vv += __shfl_xor(vv, o, 64);
      const float inv = 1.0f / sqrtf(vv*(1.f/128.f)+EPS_);
      DV[lane]    = da*inv*plg[lane] + plb[lane];
      DV[lane+64] = dc*inv*plg[lane+64] + plb[lane+64];
    }
    __syncthreads();
    {
      const float dvj = DV[j];
      #pragma unroll
      for (int t = 0; t < 26; ++t) if (t < nr) {
        float v = dvj * kp_r[t];
        #pragma unroll
        for (int o = 32; o; o >>= 1) v += __shfl_xor(v, o, 64);
        if (lane == 0) RED[w1*256 + r0 + t] = v;
      }
    }
    __syncthreads();
    if (tid < N_) {
      const float acc = RED[tid] + RED[256+tid];
      BUF[tid] = (MB[tid] > 0.f) ? NEG_INF : acc*inv_sqrt_h;
    }
    __syncthreads();
    if (tid < 64) {
      const bool m1v = (MB[lane] > 0.f);
      const bool m2v = (lane+64 >= N_) || (MB[lane+64] > 0.f);
      const bool allmb = __all(m1v && m2v);
      float c1 = BUF[lane] / Tf;
      float c2 = (lane+64 < N_) ? BUF[lane+64] / Tf : NEG_INF;
      if (allmb) { c1 = 0.f; c2 = (lane+64 < N_) ? 0.f : NEG_INF; }
      float mx = fmaxf(c1, c2);
      #pragma unroll
      for (int o = 32; o; o >>= 1) mx = fmaxf(mx, __shfl_xor(mx, o, 64));
      float e1 = expf(c1-mx);
      float e2 = (lane+64 < N_) ? expf(c2-mx) : 0.f;
      float ssum = e1+e2;
      #pragma unroll
      for (int o = 32; o; o >>= 1) ssum += __shfl_xor(ssum, o, 64);
      float p1 = e1/ssum + 1e-10f;
      float p2 = (lane+64 < N_) ? (e2/ssum + 1e-10f) : 0.f;
      float psum = p1+p2;
      #pragma unroll
      for (int o = 32; o; o >>= 1) psum += __shfl_xor(psum, o, 64);
      float bv = p1; int bi = lane;
      if (p2 > bv) { bv = p2; bi = lane+64; }
      #pragma unroll
      for (int o = 32; o; o >>= 1) {
        float ov = __shfl_xor(bv, o, 64);
        int   oi = __shfl_xor(bi, o, 64);
        if (ov > bv || (ov == bv && oi < bi)) { bv = ov; bi = oi; }
      }
      float lp = logf(bv/psum);
      if (SCI[3] >= N_-1) lp = 0.f;
      if (lane == 0) {
        SCF[2] += lp;
        const float sel = dem[(size_t)b*N_+bi];
        SCF[1] = (bi == 0) ? capac[b] : (SCF[1]-sel);
        SCI[0] = bi;
        out[(size_t)b*(ns+2)+1+i] = (float)bi;
      }
    }
    __syncthreads();
  }
  if (tid == 0) {
    const int last = SCI[0];
    out[(size_t)b*(ns+2)] = 0.f;
    out[(size_t)b*(ns+2)+ns+1] = (last == 0) ? -1.f : 0.f;
    out[(size_t)Bv*(ns+2)+b] = SCF[2];
  }
}

extern "C" void kernel_launch(void* const* d_in, const int* in_sizes, int n_in,
                              void* d_out, int out_size, void* d_ws, size_t ws_size,
                              hipStream_t stream) {
  const int Bv = in_sizes[0] / (N_ * H_);   // 1024
  const int ns = out_size / Bv - 3;         // 120
  // Deterministic per call: opt the 2-batch kernel into >64KB dynamic LDS.
  hipError_t e = hipFuncSetAttribute(
      reinterpret_cast<const void*>(gat_decoder2),
      hipFuncAttributeMaxDynamicSharedMemorySize, LDS_BYTES2);
  if (e == hipSuccess && (Bv % 2) == 0) {
    gat_decoder2<<<dim3(Bv / 2), dim3(512), LDS_BYTES2, stream>>>(
        (const float*)d_in[0],  (const float*)d_in[1],  (const float*)d_in[2],
        (const float*)d_in[3],  (const float*)d_in[4],  (const float*)d_in[5],
        (const float*)d_in[6],  (const float*)d_in[7],  (const float*)d_in[8],
        (const float*)d_in[9],  (const float*)d_in[10], (const float*)d_in[11],
        (const float*)d_in[12], (const float*)d_in[13], (const float*)d_in[14],
        (const int*)d_in[16],
        (float*)d_out, Bv, ns);
  } else {
    gat_decoder_fb<<<dim3(Bv), dim3(512), 0, stream>>>(
        (const float*)d_in[0],  (const float*)d_in[1],  (const float*)d_in[2],
        (const float*)d_in[3],  (const float*)d_in[4],  (const float*)d_in[5],
        (const float*)d_in[6],  (const float*)d_in[7],  (const float*)d_in[8],
        (const float*)d_in[9],  (const float*)d_in[10], (const float*)d_in[11],
        (const float*)d_in[12], (const float*)d_in[13], (const float*)d_in[14],
        (const int*)d_in[16],
        (float*)d_out, Bv, ns);
  }
}

// Round 9
// 3106.957 us; speedup vs baseline: 4.8055x; 4.8055x over previous
//
#include <hip/hip_runtime.h>
#include <math.h>

// Problem constants (fixed by the reference)
constexpr int N_ = 101, H_ = 128;
constexpr int SK = 129;              // padded LDS stride for K table
constexpr float EPS_ = 1e-5f;

// LDS layout (float words) — 14,744 words = 58,976 B (< 64 KiB)
constexpr int OFF_KH  = 0;                    // 13032: K table (also Kp staging)
constexpr int OFF_AT  = 13032;                // 816: attention weights (8 heads x 101)
constexpr int OFF_DRAW = OFF_AT + 816;        // 128: raw decoder vector
constexpr int OFF_DV  = OFF_DRAW + 128;       // 128: LN(d)
constexpr int OFF_XV  = OFF_DV + 128;         // 128: x = attn@V
constexpr int OFF_YR  = OFF_XV + 128;         // 128: raw y = x@wo
constexpr int OFF_XN  = OFF_YR + 128;         // 128: LN(y)
constexpr int OFF_CP  = OFF_XN + 128;         // 128: comp
constexpr int LDS_WORDS = OFF_CP + 128;

#define WSUM(v) { v += __shfl_xor(v,1,64); v += __shfl_xor(v,2,64); v += __shfl_xor(v,4,64); \
                  v += __shfl_xor(v,8,64); v += __shfl_xor(v,16,64); v += __shfl_xor(v,32,64); }
#define WMAX(v) { v = fmaxf(v,__shfl_xor(v,1,64)); v = fmaxf(v,__shfl_xor(v,2,64)); \
                  v = fmaxf(v,__shfl_xor(v,4,64)); v = fmaxf(v,__shfl_xor(v,8,64)); \
                  v = fmaxf(v,__shfl_xor(v,16,64)); v = fmaxf(v,__shfl_xor(v,32,64)); }

__global__ __launch_bounds__(512, 2) void gat_decoder(
    const float* __restrict__ enc, const float* __restrict__ pool,
    const float* __restrict__ capac, const float* __restrict__ dem,
    const float* __restrict__ fcw, const float* __restrict__ fc1w,
    const float* __restrict__ lng, const float* __restrict__ lnb,
    const float* __restrict__ wq, const float* __restrict__ wk,
    const float* __restrict__ wvm, const float* __restrict__ wo,
    const float* __restrict__ kpw, const float* __restrict__ plg,
    const float* __restrict__ plb, const int* __restrict__ tp,
    float* __restrict__ out, int Bv, int ns)
{
  __shared__ float sm[LDS_WORDS];
  const int tid  = threadIdx.x;
  const int b    = blockIdx.x;
  const int lane = tid & 63;
  const int wvid = tid >> 6;        // wave id 0..7 (= head id)
  const int lc   = lane & 15;       // local column
  const int sl   = lane >> 4;       // k-slice 0..3 within wave
  const int col  = wvid * 16 + lc;  // output column owned by this thread
  const int n1 = lane, n2 = lane + 64;

  const float NEG_INF = -__builtin_inff();
  int ti = tp[0];
  float Tf = (ti > 1000000 || ti < -1000000) ? __int_as_float((int)ti) : (float)ti;
  const float inv_sqrt_h = 1.0f / sqrtf(128.0f);
  const float PSUM_CONST = 1.0f + (float)N_ * 1e-10f;

  const float* encb = enc + (size_t)b * (N_ * H_);

  float* KH  = sm + OFF_KH;  float* AT = sm + OFF_AT;
  float* DRAW = sm + OFF_DRAW; float* DV = sm + OFF_DV;
  float* XV = sm + OFF_XV;   float* YR = sm + OFF_YR;
  float* XN = sm + OFF_XN;   float* CP = sm + OFF_CP;

  // ---------- (a) Kp col-layout into KH staging (wave-uniform enc reads) ----------
  {
    const int j3 = tid & 127;
    const int g3 = __builtin_amdgcn_readfirstlane(tid >> 7);
    const int r03 = g3 * 26, nr3 = (g3 == 3) ? 23 : 26;
    float acc[26];
    #pragma unroll
    for (int t = 0; t < 26; ++t) acc[t] = 0.f;
    for (int k0 = 0; k0 < H_; k0 += 8) {
      float w8[8];
      #pragma unroll
      for (int kk = 0; kk < 8; ++kk) w8[kk] = kpw[(k0 + kk) * H_ + j3];
      #pragma unroll
      for (int t = 0; t < 26; ++t) if (t < nr3) {
        const float* ep = encb + (r03 + t) * H_ + k0;
        #pragma unroll
        for (int kk = 0; kk < 8; ++kk) acc[t] = fmaf(ep[kk], w8[kk], acc[t]);
      }
    }
    #pragma unroll
    for (int t = 0; t < 26; ++t) if (t < nr3) KH[(r03 + t) * SK + j3] = acc[t];
  }
  __syncthreads();
  // ---------- (c) transposed Kp registers: kpT[r] = Kp[n=col][sl*32+r] ----------
  float kpT[32];
  {
    const int neff = (col < N_) ? col : (N_ - 1);
    const float* src = KH + neff * SK + sl * 32;
    #pragma unroll
    for (int r = 0; r < 32; ++r) kpT[r] = src[r];
  }
  __syncthreads();
  // ---------- (e) K col-layout into KH ----------
  {
    const int j3 = tid & 127;
    const int g3 = __builtin_amdgcn_readfirstlane(tid >> 7);
    const int r03 = g3 * 26, nr3 = (g3 == 3) ? 23 : 26;
    float acc[26];
    #pragma unroll
    for (int t = 0; t < 26; ++t) acc[t] = 0.f;
    for (int k0 = 0; k0 < H_; k0 += 8) {
      float w8[8];
      #pragma unroll
      for (int kk = 0; kk < 8; ++kk) w8[kk] = wk[(k0 + kk) * H_ + j3];
      #pragma unroll
      for (int t = 0; t < 26; ++t) if (t < nr3) {
        const float* ep = encb + (r03 + t) * H_ + k0;
        #pragma unroll
        for (int kk = 0; kk < 8; ++kk) acc[t] = fmaf(ep[kk], w8[kk], acc[t]);
      }
    }
    #pragma unroll
    for (int t = 0; t < 26; ++t) if (t < nr3) KH[(r03 + t) * SK + j3] = acc[t];
  }
  // ---------- (f) V col-slices: vh[t] = V[sl*26+t][col] ----------
  float vh[26];
  {
    const int r0v = sl * 26, nrv = (sl == 3) ? 23 : 26;
    #pragma unroll
    for (int t = 0; t < 26; ++t) vh[t] = 0.f;
    for (int k0 = 0; k0 < H_; k0 += 8) {
      float w8[8];
      #pragma unroll
      for (int kk = 0; kk < 8; ++kk) w8[kk] = wvm[(k0 + kk) * H_ + col];
      #pragma unroll
      for (int t = 0; t < 26; ++t) if (t < nrv) {
        const float* ep = encb + (r0v + t) * H_ + k0;   // uniform within 16-lane group
        #pragma unroll
        for (int kk = 0; kk < 8; ++kk) vh[t] = fmaf(ep[kk], w8[kk], vh[t]);
      }
    }
  }
  // ---------- weights: rows sl*32..+31, column col ----------
  float fc_r[32], wq_r[32], wo_r[32];
  #pragma unroll
  for (int r = 0; r < 32; ++r) {
    fc_r[r] = fcw[(sl * 32 + r) * H_ + col];
    wq_r[r] = wq[(sl * 32 + r) * H_ + col];
    wo_r[r] = wo[(sl * 32 + r) * H_ + col];
  }
  const float fcap = fcw[128 * H_ + col];
  // pool_proc[col]
  float pp;
  {
    const float* pb = pool + (size_t)b * H_;
    float p = 0.f;
    #pragma unroll
    for (int r = 0; r < 32; ++r) p = fmaf(pb[sl * 32 + r], fc1w[(sl * 32 + r) * H_ + col], p);
    p += __shfl_xor(p, 16, 64); p += __shfl_xor(p, 32, 64);
    pp = p;
  }
  // ---------- per-wave redundant decode state ----------
  const float capv = capac[b];
  float cap = capv, lpsum = 0.f;
  float demA = dem[(size_t)b * N_ + n1];
  float demC = (n2 < N_) ? dem[(size_t)b * N_ + n2] : 0.f;
  const float lngA = lng[n1], lngC = lng[n2 & 127];
  const float lnbA = lnb[n1], lnbC = lnb[n2 & 127];
  const float plgA = plg[n1], plgC = plg[n2 & 127];
  const float plbA = plb[n1], plbC = plb[n2 & 127];
  int vis = 0, pidx = 0;
  bool m1a = false, m1c = false, mbA, mbB;
  {
    bool infA = (n1 >= 1) && (demA > cap);
    bool infB = (n2 >= N_) || (demC > cap);
    bool feasA = (n1 >= 1) && !infA;
    bool feasB = (n2 < N_) && !infB;
    const bool anyf = __any(feasA || feasB);
    mbA = (n1 == 0) ? anyf : infA;
    mbB = infB;
  }
  __syncthreads();   // K table + everything ready

  // ---------- decode loop: 6 barriers/step, all phases all-wave ----------
  for (int i = 0; i < ns; ++i) {
    const int pu = __builtin_amdgcn_readfirstlane(pidx);

    // B: d[col] = enc[pidx] @ fc_w + cap*fcap + pp   (in-wave reduce)
    {
      const float* ep = encb + (size_t)pu * H_ + sl * 32;
      float p = 0.f;
      #pragma unroll
      for (int r = 0; r < 32; ++r) p = fmaf(fc_r[r], ep[r], p);
      p += __shfl_xor(p, 16, 64); p += __shfl_xor(p, 32, 64);
      p += cap * fcap + pp;
      if (sl == 0) DRAW[col] = p;
    }
    __syncthreads();                                            // bar1

    // LN(dec) — all waves redundantly; wave 0 publishes DV
    {
      const float DA = DRAW[n1], DC = DRAW[n2 & 127];
      float s1 = DA + DC;
      WSUM(s1);
      const float mu = s1 * (1.f / 128.f);
      const float da = DA - mu, dc = DC - mu;
      float vv = da * da + dc * dc;
      WSUM(vv);
      const float inv = 1.0f / sqrtf(vv * (1.f / 128.f) + EPS_);
      if (wvid == 0) {
        DV[n1] = da * inv * lngA + lnbA;
        DV[n2 & 127] = dc * inv * lngC + lnbC;
      }
    }
    __syncthreads();                                            // bar2

    // Q/logits/softmax (wave = head): q in-wave, K from LDS, attn written same-wave
    {
      const float* dvp = DV + sl * 32;
      float q = 0.f;
      #pragma unroll
      for (int r = 0; r < 32; ++r) q = fmaf(wq_r[r], dvp[r], q);
      q += __shfl_xor(q, 16, 64); q += __shfl_xor(q, 32, 64);
      float qd[16];
      #pragma unroll
      for (int d = 0; d < 16; ++d) qd[d] = __shfl(q, d, 64);
      const float* k1 = KH + n1 * SK + wvid * 16;
      float a1 = 0.f;
      #pragma unroll
      for (int d = 0; d < 16; ++d) a1 = fmaf(qd[d], k1[d], a1);
      a1 = mbA ? NEG_INF : a1 * 0.25f;
      float a2 = NEG_INF;
      if (n2 < N_) {
        const float* k2 = KH + n2 * SK + wvid * 16;
        float t2 = 0.f;
        #pragma unroll
        for (int d = 0; d < 16; ++d) t2 = fmaf(qd[d], k2[d], t2);
        a2 = mbB ? NEG_INF : t2 * 0.25f;
      }
      float mx = fmaxf(a1, a2);
      WMAX(mx);
      float e1 = expf(a1 - mx);
      float e2 = (n2 < N_) ? expf(a2 - mx) : 0.f;
      float ss = e1 + e2;
      WSUM(ss);
      AT[wvid * N_ + n1] = e1 / ss;
      if (n2 < N_) AT[wvid * N_ + n2] = e2 / ss;
    }
    // X: x[col] = attn(head wvid) @ V — reads SAME wave's AT writes (no barrier)
    {
      const float* aw = AT + wvid * N_ + sl * 26;
      const int nrv = (sl == 3) ? 23 : 26;
      float x = 0.f;
      #pragma unroll
      for (int t = 0; t < 26; ++t) if (t < nrv) x = fmaf(aw[t], vh[t], x);
      x += __shfl_xor(x, 16, 64); x += __shfl_xor(x, 32, 64);
      if (sl == 0) XV[col] = x;
    }
    __syncthreads();                                            // bar3

    // Y: y[col] = x @ wo (in-wave reduce)
    {
      const float* xp = XV + sl * 32;
      float y = 0.f;
      #pragma unroll
      for (int r = 0; r < 32; ++r) y = fmaf(wo_r[r], xp[r], y);
      y += __shfl_xor(y, 16, 64); y += __shfl_xor(y, 32, 64);
      if (sl == 0) YR[col] = y;
    }
    __syncthreads();                                            // bar4

    // LN(ptr) — all waves; wave 0 publishes XN
    {
      const float YA = YR[n1], YC = YR[n2 & 127];
      float s1 = YA + YC;
      WSUM(s1);
      const float mu = s1 * (1.f / 128.f);
      const float da = YA - mu, dc = YC - mu;
      float vv = da * da + dc * dc;
      WSUM(vv);
      const float inv = 1.0f / sqrtf(vv * (1.f / 128.f) + EPS_);
      if (wvid == 0) {
        XN[n1] = da * inv * plgA + plbA;
        XN[n2 & 127] = dc * inv * plgC + plbC;
      }
    }
    __syncthreads();                                            // bar5

    // C: comp[n=col] = xn @ Kp[n]  (4th matvec via transposed Kp regs)
    {
      const float* xp = XN + sl * 32;
      float c = 0.f;
      #pragma unroll
      for (int r = 0; r < 32; ++r) c = fmaf(kpT[r], xp[r], c);
      c += __shfl_xor(c, 16, 64); c += __shfl_xor(c, 32, 64);
      if (sl == 0 && col < N_) CP[col] = c;
    }
    __syncthreads();                                            // bar6

    // AM — all waves redundantly: argmax, lp, state, next masks (registers)
    {
      const bool allmb = __all(mbA && mbB);
      float c1 = mbA ? NEG_INF : CP[n1] * inv_sqrt_h / Tf;
      float c2 = (n2 < N_ && !mbB) ? CP[n2 & 127] * inv_sqrt_h / Tf : NEG_INF;
      if (allmb) { c1 = 0.f; c2 = (n2 < N_) ? 0.f : NEG_INF; }
      float bv = c1; int bi = n1;
      if (c2 > bv) { bv = c2; bi = n2; }
      #pragma unroll
      for (int o = 32; o; o >>= 1) {
        float ov = __shfl_xor(bv, o, 64);
        int   oi = __shfl_xor(bi, o, 64);
        if (ov > bv || (ov == bv && oi < bi)) { bv = ov; bi = oi; }
      }
      float e1 = expf(c1 - bv);
      float e2 = (n2 < N_) ? expf(c2 - bv) : 0.f;
      float ss = e1 + e2;
      WSUM(ss);
      float lp = logf((1.0f / ss + 1e-10f) / PSUM_CONST);
      if (vis >= N_ - 1) lp = 0.f;
      lpsum += lp;
      const float dsel = (bi < 64) ? __shfl(demA, bi, 64) : __shfl(demC, bi - 64, 64);
      cap = (bi == 0) ? capv : (cap - dsel);
      if (bi != 0) {
        const bool newly = ((bi == n1) && !m1a) || ((bi == n2) && !m1c);
        if (__any(newly)) vis += 1;
        m1a = m1a || (bi == n1);
        m1c = m1c || (bi == n2);
      }
      bool infA = (n1 >= 1) && (m1a || demA > cap);
      bool infB = (n2 >= N_) || m1c || (demC > cap);
      bool feasA = (n1 >= 1) && !infA;
      bool feasB = (n2 < N_) && !infB;
      const bool anyf = __any(feasA || feasB);
      const bool depot_m = anyf && (bi == 0);
      mbA = (n1 == 0) ? depot_m : infA;
      mbB = infB;
      pidx = bi;
      if (wvid == 0 && lane == 0) out[(size_t)b * (ns + 2) + 1 + i] = (float)bi;
    }
    // next B writes DRAW: its prior readers (LN1, pre-bar2) are >=4 barriers past. safe.
  }

  if (wvid == 0 && lane == 0) {
    out[(size_t)b * (ns + 2)] = 0.f;
    out[(size_t)b * (ns + 2) + ns + 1] = (pidx == 0) ? -1.f : 0.f;
    out[(size_t)Bv * (ns + 2) + b] = lpsum;   // log_p
  }
}

extern "C" void kernel_launch(void* const* d_in, const int* in_sizes, int n_in,
                              void* d_out, int out_size, void* d_ws, size_t ws_size,
                              hipStream_t stream) {
  const int Bv = in_sizes[0] / (N_ * H_);   // 1024
  const int ns = out_size / Bv - 3;         // B*(ns+2) actions + B log_p => 120
  gat_decoder<<<dim3(Bv), dim3(512), 0, stream>>>(
      (const float*)d_in[0],  (const float*)d_in[1],  (const float*)d_in[2],
      (const float*)d_in[3],  (const float*)d_in[4],  (const float*)d_in[5],
      (const float*)d_in[6],  (const float*)d_in[7],  (const float*)d_in[8],
      (const float*)d_in[9],  (const float*)d_in[10], (const float*)d_in[11],
      (const float*)d_in[12], (const float*)d_in[13], (const float*)d_in[14],
      (const int*)d_in[16],
      (float*)d_out, Bv, ns);
}

// Round 10
// 2977.154 us; speedup vs baseline: 5.0150x; 1.0436x over previous
//
#include <hip/hip_runtime.h>
#include <math.h>

// Problem constants (fixed by the reference)
constexpr int N_ = 101, H_ = 128;
constexpr int SK = 129;              // padded LDS stride for K table
constexpr float EPS_ = 1e-5f;

// LDS layout (float words) — 14,744 words = 58,976 B (< 64 KiB)
constexpr int OFF_KH  = 0;                    // 13032: K table (also Kp staging)
constexpr int OFF_AT  = 13032;                // 816: attention weights (8 heads x 101)
constexpr int OFF_DRAW = OFF_AT + 816;        // 128: raw decoder vector
constexpr int OFF_DV  = OFF_DRAW + 128;       // 128: LN(d)        (16B aligned)
constexpr int OFF_XV  = OFF_DV + 128;         // 128: x = attn@V   (16B aligned)
constexpr int OFF_YR  = OFF_XV + 128;         // 128: raw y = x@wo
constexpr int OFF_XN  = OFF_YR + 128;         // 128: LN(y)        (16B aligned)
constexpr int OFF_CP  = OFF_XN + 128;         // 128: comp
constexpr int LDS_WORDS = OFF_CP + 128;

#define WSUM(v) { v += __shfl_xor(v,1,64); v += __shfl_xor(v,2,64); v += __shfl_xor(v,4,64); \
                  v += __shfl_xor(v,8,64); v += __shfl_xor(v,16,64); v += __shfl_xor(v,32,64); }
#define WMAX(v) { v = fmaxf(v,__shfl_xor(v,1,64)); v = fmaxf(v,__shfl_xor(v,2,64)); \
                  v = fmaxf(v,__shfl_xor(v,4,64)); v = fmaxf(v,__shfl_xor(v,8,64)); \
                  v = fmaxf(v,__shfl_xor(v,16,64)); v = fmaxf(v,__shfl_xor(v,32,64)); }

__device__ __forceinline__ float rdlane(float v, int l) {
  return __int_as_float(__builtin_amdgcn_readlane(__float_as_int(v), l));
}

__global__ __launch_bounds__(512, 2) void gat_decoder(
    const float* __restrict__ enc, const float* __restrict__ pool,
    const float* __restrict__ capac, const float* __restrict__ dem,
    const float* __restrict__ fcw, const float* __restrict__ fc1w,
    const float* __restrict__ lng, const float* __restrict__ lnb,
    const float* __restrict__ wq, const float* __restrict__ wk,
    const float* __restrict__ wvm, const float* __restrict__ wo,
    const float* __restrict__ kpw, const float* __restrict__ plg,
    const float* __restrict__ plb, const int* __restrict__ tp,
    float* __restrict__ out, int Bv, int ns)
{
  __shared__ float sm[LDS_WORDS];
  const int tid  = threadIdx.x;
  const int b    = blockIdx.x;
  const int lane = tid & 63;
  const int wvid = tid >> 6;        // wave id 0..7 (= head id)
  const int lc   = lane & 15;       // local column
  const int sl   = lane >> 4;       // k-slice 0..3 within wave
  const int col  = wvid * 16 + lc;  // output column owned by this thread
  const int n1 = lane, n2 = lane + 64;

  const float NEG_INF = -__builtin_inff();
  int ti = tp[0];
  float Tf = (ti > 1000000 || ti < -1000000) ? __int_as_float((int)ti) : (float)ti;
  const float inv_sqrt_h = 1.0f / sqrtf(128.0f);
  const float PSUM_CONST = 1.0f + (float)N_ * 1e-10f;

  const float* encb = enc + (size_t)b * (N_ * H_);

  float* KH  = sm + OFF_KH;  float* AT = sm + OFF_AT;
  float* DRAW = sm + OFF_DRAW; float* DV = sm + OFF_DV;
  float* XV = sm + OFF_XV;   float* YR = sm + OFF_YR;
  float* XN = sm + OFF_XN;   float* CP = sm + OFF_CP;

  // ---------- (a) Kp col-layout into KH staging (wave-uniform enc reads) ----------
  {
    const int j3 = tid & 127;
    const int g3 = __builtin_amdgcn_readfirstlane(tid >> 7);
    const int r03 = g3 * 26, nr3 = (g3 == 3) ? 23 : 26;
    float acc[26];
    #pragma unroll
    for (int t = 0; t < 26; ++t) acc[t] = 0.f;
    for (int k0 = 0; k0 < H_; k0 += 8) {
      float w8[8];
      #pragma unroll
      for (int kk = 0; kk < 8; ++kk) w8[kk] = kpw[(k0 + kk) * H_ + j3];
      #pragma unroll
      for (int t = 0; t < 26; ++t) if (t < nr3) {
        const float* ep = encb + (r03 + t) * H_ + k0;
        #pragma unroll
        for (int kk = 0; kk < 8; ++kk) acc[t] = fmaf(ep[kk], w8[kk], acc[t]);
      }
    }
    #pragma unroll
    for (int t = 0; t < 26; ++t) if (t < nr3) KH[(r03 + t) * SK + j3] = acc[t];
  }
  __syncthreads();
  // ---------- (c) transposed Kp registers: kpT[r] = Kp[n=col][sl*32+r] ----------
  float kpT[32];
  {
    const int neff = (col < N_) ? col : (N_ - 1);
    const float* src = KH + neff * SK + sl * 32;
    #pragma unroll
    for (int r = 0; r < 32; ++r) kpT[r] = src[r];
  }
  __syncthreads();
  // ---------- (e) K col-layout into KH ----------
  {
    const int j3 = tid & 127;
    const int g3 = __builtin_amdgcn_readfirstlane(tid >> 7);
    const int r03 = g3 * 26, nr3 = (g3 == 3) ? 23 : 26;
    float acc[26];
    #pragma unroll
    for (int t = 0; t < 26; ++t) acc[t] = 0.f;
    for (int k0 = 0; k0 < H_; k0 += 8) {
      float w8[8];
      #pragma unroll
      for (int kk = 0; kk < 8; ++kk) w8[kk] = wk[(k0 + kk) * H_ + j3];
      #pragma unroll
      for (int t = 0; t < 26; ++t) if (t < nr3) {
        const float* ep = encb + (r03 + t) * H_ + k0;
        #pragma unroll
        for (int kk = 0; kk < 8; ++kk) acc[t] = fmaf(ep[kk], w8[kk], acc[t]);
      }
    }
    #pragma unroll
    for (int t = 0; t < 26; ++t) if (t < nr3) KH[(r03 + t) * SK + j3] = acc[t];
  }
  // ---------- (f) V col-slices: vh[t] = V[sl*26+t][col] ----------
  float vh[26];
  {
    const int r0v = sl * 26, nrv = (sl == 3) ? 23 : 26;
    #pragma unroll
    for (int t = 0; t < 26; ++t) vh[t] = 0.f;
    for (int k0 = 0; k0 < H_; k0 += 8) {
      float w8[8];
      #pragma unroll
      for (int kk = 0; kk < 8; ++kk) w8[kk] = wvm[(k0 + kk) * H_ + col];
      #pragma unroll
      for (int t = 0; t < 26; ++t) if (t < nrv) {
        const float* ep = encb + (r0v + t) * H_ + k0;   // uniform within 16-lane group
        #pragma unroll
        for (int kk = 0; kk < 8; ++kk) vh[t] = fmaf(ep[kk], w8[kk], vh[t]);
      }
    }
  }
  // ---------- weights: rows sl*32..+31, column col ----------
  float fc_r[32], wq_r[32], wo_r[32];
  #pragma unroll
  for (int r = 0; r < 32; ++r) {
    fc_r[r] = fcw[(sl * 32 + r) * H_ + col];
    wq_r[r] = wq[(sl * 32 + r) * H_ + col];
    wo_r[r] = wo[(sl * 32 + r) * H_ + col];
  }
  const float fcap = fcw[128 * H_ + col];
  // pool_proc[col]
  float pp;
  {
    const float* pb = pool + (size_t)b * H_;
    float p = 0.f;
    #pragma unroll
    for (int r = 0; r < 32; ++r) p = fmaf(pb[sl * 32 + r], fc1w[(sl * 32 + r) * H_ + col], p);
    p += __shfl_xor(p, 16, 64); p += __shfl_xor(p, 32, 64);
    pp = p;
  }
  // ---------- per-wave redundant decode state ----------
  const float capv = capac[b];
  float cap = capv, lpsum = 0.f;
  float demA = dem[(size_t)b * N_ + n1];
  float demC = (n2 < N_) ? dem[(size_t)b * N_ + n2] : 0.f;
  const float lngA = lng[n1], lngC = lng[n2 & 127];
  const float lnbA = lnb[n1], lnbC = lnb[n2 & 127];
  const float plgA = plg[n1], plgC = plg[n2 & 127];
  const float plbA = plb[n1], plbC = plb[n2 & 127];
  int vis = 0, pidx = 0;
  bool m1a = false, m1c = false, mbA, mbB;
  {
    bool infA = (n1 >= 1) && (demA > cap);
    bool infB = (n2 >= N_) || (demC > cap);
    bool feasA = (n1 >= 1) && !infA;
    bool feasB = (n2 < N_) && !infB;
    const bool anyf = __any(feasA || feasB);
    mbA = (n1 == 0) ? anyf : infA;
    mbB = infB;
  }
  __syncthreads();   // K table + everything ready

  // ---------- decode loop: 6 barriers/step ----------
  for (int i = 0; i < ns; ++i) {
    const int pu = __builtin_amdgcn_readfirstlane(pidx);

    // B: d[col] = enc[pidx] @ fc_w + cap*fcap + pp   (in-wave reduce)
    {
      const float* ep = encb + (size_t)pu * H_ + sl * 32;
      float p = 0.f;
      #pragma unroll
      for (int r = 0; r < 32; ++r) p = fmaf(fc_r[r], ep[r], p);
      p += __shfl_xor(p, 16, 64); p += __shfl_xor(p, 32, 64);
      p += cap * fcap + pp;
      if (sl == 0) DRAW[col] = p;
    }
    __syncthreads();                                            // bar1

    // LN(dec) — wave 0 only (others wait; same critical path, 1/8 the DS ops)
    if (wvid == 0) {
      const float DA = DRAW[n1], DC = DRAW[n2 & 127];
      float s1 = DA + DC;
      WSUM(s1);
      const float mu = s1 * (1.f / 128.f);
      const float da = DA - mu, dc = DC - mu;
      float vv = da * da + dc * dc;
      WSUM(vv);
      const float inv = 1.0f / sqrtf(vv * (1.f / 128.f) + EPS_);
      DV[n1] = da * inv * lngA + lnbA;
      DV[n2 & 127] = dc * inv * lngC + lnbC;
    }
    __syncthreads();                                            // bar2

    // Q/logits/softmax (wave = head): q in-wave (b128 reads), qd via readlane
    {
      const float4* dv4 = (const float4*)(DV + sl * 32);
      float q = 0.f;
      #pragma unroll
      for (int r4 = 0; r4 < 8; ++r4) {                 // exact r9 summation order
        const float4 u = dv4[r4];
        q = fmaf(wq_r[r4 * 4 + 0], u.x, q);
        q = fmaf(wq_r[r4 * 4 + 1], u.y, q);
        q = fmaf(wq_r[r4 * 4 + 2], u.z, q);
        q = fmaf(wq_r[r4 * 4 + 3], u.w, q);
      }
      q += __shfl_xor(q, 16, 64); q += __shfl_xor(q, 32, 64);
      const float* k1 = KH + n1 * SK + wvid * 16;
      const float* k2 = KH + ((n2 < N_) ? n2 : n1) * SK + wvid * 16;
      float a1 = 0.f, a2r = 0.f;
      #pragma unroll
      for (int d = 0; d < 16; ++d) {
        const float qdv = rdlane(q, d);                // uniform: SALU, no DS op
        a1  = fmaf(qdv, k1[d], a1);
        a2r = fmaf(qdv, k2[d], a2r);
      }
      a1 = mbA ? NEG_INF : a1 * 0.25f;
      float a2 = (n2 < N_ && !mbB) ? a2r * 0.25f : NEG_INF;
      float mx = fmaxf(a1, a2);
      WMAX(mx);
      float e1 = expf(a1 - mx);
      float e2 = (n2 < N_) ? expf(a2 - mx) : 0.f;
      float ss = e1 + e2;
      WSUM(ss);
      AT[wvid * N_ + n1] = e1 / ss;
      if (n2 < N_) AT[wvid * N_ + n2] = e2 / ss;
    }
    // X: x[col] = attn(head wvid) @ V — same-wave AT reads (no barrier)
    {
      const float* aw = AT + wvid * N_ + sl * 26;
      const int nrv = (sl == 3) ? 23 : 26;
      float x = 0.f;
      #pragma unroll
      for (int t = 0; t < 26; ++t) if (t < nrv) x = fmaf(aw[t], vh[t], x);
      x += __shfl_xor(x, 16, 64); x += __shfl_xor(x, 32, 64);
      if (sl == 0) XV[col] = x;
    }
    __syncthreads();                                            // bar3

    // Y: y[col] = x @ wo (b128 reads, in-wave reduce)
    {
      const float4* xp4 = (const float4*)(XV + sl * 32);
      float y = 0.f;
      #pragma unroll
      for (int r4 = 0; r4 < 8; ++r4) {
        const float4 u = xp4[r4];
        y = fmaf(wo_r[r4 * 4 + 0], u.x, y);
        y = fmaf(wo_r[r4 * 4 + 1], u.y, y);
        y = fmaf(wo_r[r4 * 4 + 2], u.z, y);
        y = fmaf(wo_r[r4 * 4 + 3], u.w, y);
      }
      y += __shfl_xor(y, 16, 64); y += __shfl_xor(y, 32, 64);
      if (sl == 0) YR[col] = y;
    }
    __syncthreads();                                            // bar4

    // LN(ptr) — wave 0 only
    if (wvid == 0) {
      const float YA = YR[n1], YC = YR[n2 & 127];
      float s1 = YA + YC;
      WSUM(s1);
      const float mu = s1 * (1.f / 128.f);
      const float da = YA - mu, dc = YC - mu;
      float vv = da * da + dc * dc;
      WSUM(vv);
      const float inv = 1.0f / sqrtf(vv * (1.f / 128.f) + EPS_);
      XN[n1] = da * inv * plgA + plbA;
      XN[n2 & 127] = dc * inv * plgC + plbC;
    }
    __syncthreads();                                            // bar5

    // C: comp[n=col] = xn @ Kp[n]  (b128 reads, transposed Kp regs)
    {
      const float4* xp4 = (const float4*)(XN + sl * 32);
      float c = 0.f;
      #pragma unroll
      for (int r4 = 0; r4 < 8; ++r4) {
        const float4 u = xp4[r4];
        c = fmaf(kpT[r4 * 4 + 0], u.x, c);
        c = fmaf(kpT[r4 * 4 + 1], u.y, c);
        c = fmaf(kpT[r4 * 4 + 2], u.z, c);
        c = fmaf(kpT[r4 * 4 + 3], u.w, c);
      }
      c += __shfl_xor(c, 16, 64); c += __shfl_xor(c, 32, 64);
      if (sl == 0 && col < N_) CP[col] = c;
    }
    __syncthreads();                                            // bar6

    // AM — all waves redundantly: argmax, lp, state, next masks (registers)
    {
      const bool allmb = __all(mbA && mbB);
      float c1 = mbA ? NEG_INF : CP[n1] * inv_sqrt_h / Tf;
      float c2 = (n2 < N_ && !mbB) ? CP[n2 & 127] * inv_sqrt_h / Tf : NEG_INF;
      if (allmb) { c1 = 0.f; c2 = (n2 < N_) ? 0.f : NEG_INF; }
      float bv = c1; int bi = n1;
      if (c2 > bv) { bv = c2; bi = n2; }
      #pragma unroll
      for (int o = 32; o; o >>= 1) {
        float ov = __shfl_xor(bv, o, 64);
        int   oi = __shfl_xor(bi, o, 64);
        if (ov > bv || (ov == bv && oi < bi)) { bv = ov; bi = oi; }
      }
      float e1 = expf(c1 - bv);
      float e2 = (n2 < N_) ? expf(c2 - bv) : 0.f;
      float ss = e1 + e2;
      WSUM(ss);
      float lp = logf((1.0f / ss + 1e-10f) / PSUM_CONST);
      if (vis >= N_ - 1) lp = 0.f;
      lpsum += lp;
      const int bis = __builtin_amdgcn_readfirstlane(bi);
      const float dsel = (bis < 64) ? rdlane(demA, bis) : rdlane(demC, bis - 64);
      cap = (bis == 0) ? capv : (cap - dsel);
      if (bis != 0) {
        const bool newly = ((bis == n1) && !m1a) || ((bis == n2) && !m1c);
        if (__any(newly)) vis += 1;
        m1a = m1a || (bis == n1);
        m1c = m1c || (bis == n2);
      }
      bool infA = (n1 >= 1) && (m1a || demA > cap);
      bool infB = (n2 >= N_) || m1c || (demC > cap);
      bool feasA = (n1 >= 1) && !infA;
      bool feasB = (n2 < N_) && !infB;
      const bool anyf = __any(feasA || feasB);
      const bool depot_m = anyf && (bis == 0);
      mbA = (n1 == 0) ? depot_m : infA;
      mbB = infB;
      pidx = bis;
      if (wvid == 0 && lane == 0) out[(size_t)b * (ns + 2) + 1 + i] = (float)bis;
    }
    // next B writes DRAW: its prior readers (wave0 LN1, pre-bar2) are >=4 barriers past. safe.
  }

  if (wvid == 0 && lane == 0) {
    out[(size_t)b * (ns + 2)] = 0.f;
    out[(size_t)b * (ns + 2) + ns + 1] = (pidx == 0) ? -1.f : 0.f;
    out[(size_t)Bv * (ns + 2) + b] = lpsum;   // log_p
  }
}

extern "C" void kernel_launch(void* const* d_in, const int* in_sizes, int n_in,
                              void* d_out, int out_size, void* d_ws, size_t ws_size,
                              hipStream_t stream) {
  const int Bv = in_sizes[0] / (N_ * H_);   // 1024
  const int ns = out_size / Bv - 3;         // B*(ns+2) actions + B log_p => 120
  gat_decoder<<<dim3(Bv), dim3(512), 0, stream>>>(
      (const float*)d_in[0],  (const float*)d_in[1],  (const float*)d_in[2],
      (const float*)d_in[3],  (const float*)d_in[4],  (const float*)d_in[5],
      (const float*)d_in[6],  (const float*)d_in[7],  (const float*)d_in[8],
      (const float*)d_in[9],  (const float*)d_in[10], (const float*)d_in[11],
      (const float*)d_in[12], (const float*)d_in[13], (const float*)d_in[14],
      (const int*)d_in[16],
      (float*)d_out, Bv, ns);
}